// Round 7
// baseline (1388.649 us; speedup 1.0000x reference)
//
#include <hip/hip_runtime.h>
#include <cstddef>

// ---------------- constants ----------------
#define NXI   512
#define LL    128
#define NST   128
#define NU    64
#define BATCH 32768
#define TW    1152          // 2n + l
#define EPSC  0.001f
#define KC    768           // concat K: xi(512) | eps(128) | w(128)
#define NC    576           // concat N: xi'(512) | u(64)
#define NCP   640           // NC padded to 128

typedef unsigned short u16;
typedef __attribute__((ext_vector_type(8))) short   short8;
typedef __attribute__((ext_vector_type(4))) short   short4v;
typedef __attribute__((ext_vector_type(4))) float   f32x4;

__device__ __forceinline__ u16 f2bf(float f) {
    unsigned u = __float_as_uint(f);
    u += 0x7FFFu + ((u >> 16) & 1u);   // RNE
    return (u16)(u >> 16);
}

// ---------------- fused setup: transpose+convert X -> XT (blocks 0..1295),
// build Ac = [bf16(xi) | (eps gap) | bf16(w)] (blocks 1296..11535). ----------------
__global__ __launch_bounds__(256) void k_setup(const float* __restrict__ X, u16* __restrict__ XT,
                                               const float* __restrict__ xi, const float* __restrict__ w,
                                               u16* __restrict__ Ac) {
    __shared__ float t[32][33];
    int blk = blockIdx.x;
    if (blk < 1296) {
        int tx = threadIdx.x & 31, ty = threadIdx.x >> 5;
        int bx = blk % 36, by = blk / 36;
        #pragma unroll
        for (int q = 0; q < 4; q++) {
            int r = ty + q * 8;
            t[r][tx] = X[(size_t)(by * 32 + r) * TW + bx * 32 + tx];
        }
        __syncthreads();
        #pragma unroll
        for (int q = 0; q < 4; q++) {
            int r = ty + q * 8;
            XT[(size_t)(bx * 32 + r) * TW + by * 32 + tx] = f2bf(t[tx][r]);
        }
        return;
    }
    size_t tt = (size_t)(blk - 1296) * 256 + threadIdx.x;   // chunk id, 8 elems each
    int b = (int)(tt / 80), ch = (int)(tt % 80);
    const float* src;
    int col;
    if (ch < 64) { src = xi + (size_t)b * NXI + ch * 8;        col = ch * 8; }
    else         { src = w  + (size_t)b * NST + (ch - 64) * 8; col = 640 + (ch - 64) * 8; }
    f32x4 a = ((const f32x4*)src)[0], c = ((const f32x4*)src)[1];
    short8 o;
    o[0]=(short)f2bf(a[0]); o[1]=(short)f2bf(a[1]); o[2]=(short)f2bf(a[2]); o[3]=(short)f2bf(a[3]);
    o[4]=(short)f2bf(c[0]); o[5]=(short)f2bf(c[1]); o[6]=(short)f2bf(c[2]); o[7]=(short)f2bf(c[3]);
    *(short8*)(Ac + (size_t)b * KC + col) = o;
}

// ---------------- 2-phase double-buffered bf16 MFMA GEMM: C = A @ W^T ----------------
__global__ __launch_bounds__(256) void k_gemm2(const u16* __restrict__ A, int lda,
                                               const u16* __restrict__ W, int ldw,
                                               float* __restrict__ C0, int ldc0, int nsplit,
                                               float* __restrict__ C1, int ldc1,
                                               int K, int nbx, int ntrue, int swz) {
    __shared__ __align__(16) u16 As[2][128 * 32];
    __shared__ __align__(16) u16 Bs[2][128 * 32];
    int id = blockIdx.x;
    int bx, by;
    if (swz) {
        int j = id >> 3;
        int per = (int)(gridDim.x >> 3) / nbx;     // M-bands per XCD (requires nby%8==0)
        by = (id & 7) * per + j / nbx;
        bx = j - (j / nbx) * nbx;
    } else {
        by = id / nbx;
        bx = id - by * nbx;
    }
    const int tid = threadIdx.x;
    const int wave = tid >> 6, lane = tid & 63, quad = lane >> 4, l16 = lane & 15;
    const int bm0 = by * 128, bn0 = bx * 128;
    const int srow = tid >> 2;
    const int sch = (((tid & 3) ^ ((srow >> 2) & 3))) * 8;   // pre-swizzled source chunk
    const u16* ga0 = A + (size_t)(bm0 + srow) * lda + sch;
    const u16* ga1 = ga0 + (size_t)64 * lda;
    const u16* gb0 = W + (size_t)(bn0 + srow) * ldw + sch;
    const u16* gb1 = gb0 + (size_t)64 * ldw;
    const int lo = wave * 512;     // wave-uniform LDS dest (lane-ordered, contiguous)
    const int mb = (wave >> 1) * 64, nb = (wave & 1) * 64;
    const int rch = (quad ^ (l16 >> 2)) * 8;                 // swizzled read chunk

    f32x4 acc[4][4];
    #pragma unroll
    for (int i = 0; i < 4; i++)
        #pragma unroll
        for (int j = 0; j < 4; j++) acc[i][j] = (f32x4){0.f, 0.f, 0.f, 0.f};

    const int nk = K >> 5;
    __builtin_amdgcn_global_load_lds((void*)(ga0), (void*)(As[0] + lo),        16, 0, 0);
    __builtin_amdgcn_global_load_lds((void*)(ga1), (void*)(As[0] + lo + 2048), 16, 0, 0);
    __builtin_amdgcn_global_load_lds((void*)(gb0), (void*)(Bs[0] + lo),        16, 0, 0);
    __builtin_amdgcn_global_load_lds((void*)(gb1), (void*)(Bs[0] + lo + 2048), 16, 0, 0);
    __syncthreads();
    int cur = 0;
    for (int t = 0; t < nk; ++t) {
        if (t + 1 < nk) {
            const int kt = (t + 1) << 5;
            const int nx = cur ^ 1;
            __builtin_amdgcn_global_load_lds((void*)(ga0 + kt), (void*)(As[nx] + lo),        16, 0, 0);
            __builtin_amdgcn_global_load_lds((void*)(ga1 + kt), (void*)(As[nx] + lo + 2048), 16, 0, 0);
            __builtin_amdgcn_global_load_lds((void*)(gb0 + kt), (void*)(Bs[nx] + lo),        16, 0, 0);
            __builtin_amdgcn_global_load_lds((void*)(gb1 + kt), (void*)(Bs[nx] + lo + 2048), 16, 0, 0);
        }
        const u16* as = As[cur];
        const u16* bs = Bs[cur];
        short8 af[4], bf[4];
        #pragma unroll
        for (int mt = 0; mt < 4; mt++) af[mt] = *(const short8*)&as[(mb + mt * 16 + l16) * 32 + rch];
        #pragma unroll
        for (int nt = 0; nt < 4; nt++) bf[nt] = *(const short8*)&bs[(nb + nt * 16 + l16) * 32 + rch];
        #pragma unroll
        for (int mt = 0; mt < 4; mt++)
            #pragma unroll
            for (int nt = 0; nt < 4; nt++)
                acc[mt][nt] = __builtin_amdgcn_mfma_f32_16x16x32_bf16(af[mt], bf[nt], acc[mt][nt], 0, 0, 0);
        __syncthreads();
        cur ^= 1;
    }
    #pragma unroll
    for (int mt = 0; mt < 4; mt++)
        #pragma unroll
        for (int nt = 0; nt < 4; nt++)
            #pragma unroll
            for (int r = 0; r < 4; r++) {
                int row = bm0 + mb + mt * 16 + quad * 4 + r;
                int col = bn0 + nb + nt * 16 + l16;
                if (col < ntrue) {
                    float v = acc[mt][nt][r];
                    if (col < nsplit) C0[(size_t)row * ldc0 + col] = v;
                    else              C1[(size_t)row * ldc1 + (col - nsplit)] = v;
                }
            }
}

// ---------------- derive params from H, build GJ-augmented [E | Fm B1 B2], D11, rlam, W1 ----------------
__global__ __launch_bounds__(256) void k_derive(const float* __restrict__ Hm, const float* __restrict__ Y,
                                                const float* __restrict__ B2, const float* __restrict__ D12,
                                                float* __restrict__ Agj, float* __restrict__ D11,
                                                float* __restrict__ rlam, u16* __restrict__ W1) {
    int idx = blockIdx.x * 256 + threadIdx.x;
    const int n0 = 512 * 1280, n1 = 128 * 128, n2 = 128, n3 = 128 * KC;
    if (idx < n0) {
        int i = idx / 1280, j = idx % 1280;
        float val;
        if (j < 512) {
            val = 0.5f * (Hm[(size_t)i * TW + j] + Hm[(size_t)(640 + i) * TW + 640 + j]
                          + Y[(size_t)i * 512 + j] - Y[(size_t)j * 512 + i]);
            if (i == j) val += EPSC;
        } else if (j < 1024) {
            val = Hm[(size_t)(640 + i) * TW + (j - 512)];           // Fm = H31
        } else if (j < 1152) {
            val = Hm[(size_t)(640 + i) * TW + 512 + (j - 1024)];    // B1 = H32
        } else {
            val = B2[(size_t)i * NST + (j - 1152)];
        }
        Agj[idx] = val;
        return;
    }
    idx -= n0;
    if (idx < n1) {
        int i = idx >> 7, j = idx & 127;
        D11[idx] = (j < i) ? -Hm[(size_t)(512 + i) * TW + 512 + j] : 0.f;  // -tril(H22,-1)
        return;
    }
    idx -= n1;
    if (idx < n2) {
        rlam[idx] = 2.0f / (Hm[(size_t)(512 + idx) * TW + 512 + idx] + EPSC);  // 1/(0.5*diag(H22))
        return;
    }
    idx -= n2;
    if (idx < n3) {
        int i = idx / KC, c = idx % KC;
        float v;
        if (c < 512)      v = -Hm[(size_t)(512 + i) * TW + c];      // C1 = -H21
        else if (c < 640) v = 0.f;                                  // eps slot unused for pre
        else              v = D12[(size_t)i * NST + (c - 640)];
        W1[(size_t)i * KC + c] = f2bf(v);
    }
}

// ---------------- 64x64 in-place GJ inverse, register-resident, readlane broadcast ----------------
// Single wave; lane r holds row r in 64 VGPRs. Fully unrolled k so all register
// indices are static (rule #20) and the readlane lane-select is a constant.
// No LDS, no barriers: the per-pivot serial chain is pure VALU (~readlane+cndmask+fma
// per element), vs ~750 cy/iter of LDS-round-trip+barrier in the R2/R6 variants.
// Math identical to R6's verified in-place transform:
//   tm = piv ? 1/p : -a[k]/p;  a[j] = tm*s_j + (piv ? 0 : a[j]);  a[k] = tm.
// SSA ordering guarantees each readlane sees the pre-update a[j] within the iter.
__device__ __forceinline__ void inv64_core(float* a, int r) {
    #pragma unroll
    for (int k = 0; k < 64; ++k) {
        float p  = __uint_as_float(__builtin_amdgcn_readlane(__float_as_uint(a[k]), k));
        float ip = 1.0f / p;
        float m  = a[k];
        const bool piv = (r == k);
        float tm = piv ? ip : -m * ip;
        #pragma unroll
        for (int j = 0; j < 64; ++j) {
            float sj = __uint_as_float(__builtin_amdgcn_readlane(__float_as_uint(a[j]), k));
            a[j] = fmaf(tm, sj, piv ? 0.f : a[j]);
        }
        a[k] = tm;
    }
}

// ---------------- diag block 0 inversion (block 0, wave 0, direct from global) +
// piggyback pre-GEMM (blocks 1..256): pre = Ac @ W1^T. Independent outputs, no sync. ----------------
__global__ __launch_bounds__(256) void k_diaginv0(const float* __restrict__ Agj, float* __restrict__ invD,
                                                  const u16* __restrict__ Ac, const u16* __restrict__ W1,
                                                  float* __restrict__ pre) {
    __shared__ __align__(16) u16 AsB[2][4096];
    __shared__ __align__(16) u16 BsB[2][4096];
    const int tid = threadIdx.x;
    const int id = blockIdx.x;
    if (id == 0) {
        if (tid < 64) {
            float a[64];
            #pragma unroll
            for (int j4 = 0; j4 < 16; ++j4) {
                f32x4 v = *(const f32x4*)(Agj + (size_t)tid * 1280 + j4 * 4);
                a[j4*4+0]=v[0]; a[j4*4+1]=v[1]; a[j4*4+2]=v[2]; a[j4*4+3]=v[3];
            }
            inv64_core(a, tid);
            #pragma unroll
            for (int j4 = 0; j4 < 16; ++j4)
                *(f32x4*)(invD + (size_t)tid * 64 + j4 * 4) = (f32x4){a[j4*4], a[j4*4+1], a[j4*4+2], a[j4*4+3]};
        }
        return;
    }
    // ---- pre-GEMM tile (R5-verified body), by = id-1 over M=32768 ----
    const int by = id - 1;
    const int wave = tid >> 6, lane = tid & 63, quad = lane >> 4, l16 = lane & 15;
    const int bm0 = by * 128;
    const int srow = tid >> 2;
    const int sch = (((tid & 3) ^ ((srow >> 2) & 3))) * 8;
    const u16* ga0 = Ac + (size_t)(bm0 + srow) * KC + sch;
    const u16* ga1 = ga0 + (size_t)64 * KC;
    const u16* gb0 = W1 + (size_t)srow * KC + sch;
    const u16* gb1 = gb0 + (size_t)64 * KC;
    const int lo = wave * 512;
    const int mb = (wave >> 1) * 64, nb = (wave & 1) * 64;
    const int rch = (quad ^ (l16 >> 2)) * 8;
    f32x4 acc[4][4];
    #pragma unroll
    for (int i = 0; i < 4; i++)
        #pragma unroll
        for (int j = 0; j < 4; j++) acc[i][j] = (f32x4){0.f, 0.f, 0.f, 0.f};
    __builtin_amdgcn_global_load_lds((void*)(ga0), (void*)(AsB[0] + lo),        16, 0, 0);
    __builtin_amdgcn_global_load_lds((void*)(ga1), (void*)(AsB[0] + lo + 2048), 16, 0, 0);
    __builtin_amdgcn_global_load_lds((void*)(gb0), (void*)(BsB[0] + lo),        16, 0, 0);
    __builtin_amdgcn_global_load_lds((void*)(gb1), (void*)(BsB[0] + lo + 2048), 16, 0, 0);
    __syncthreads();
    int cur = 0;
    for (int t = 0; t < 24; ++t) {
        if (t + 1 < 24) {
            const int kt = (t + 1) << 5;
            const int nx = cur ^ 1;
            __builtin_amdgcn_global_load_lds((void*)(ga0 + kt), (void*)(AsB[nx] + lo),        16, 0, 0);
            __builtin_amdgcn_global_load_lds((void*)(ga1 + kt), (void*)(AsB[nx] + lo + 2048), 16, 0, 0);
            __builtin_amdgcn_global_load_lds((void*)(gb0 + kt), (void*)(BsB[nx] + lo),        16, 0, 0);
            __builtin_amdgcn_global_load_lds((void*)(gb1 + kt), (void*)(BsB[nx] + lo + 2048), 16, 0, 0);
        }
        const u16* as = AsB[cur];
        const u16* bs = BsB[cur];
        short8 af[4], bf[4];
        #pragma unroll
        for (int mt = 0; mt < 4; mt++) af[mt] = *(const short8*)&as[(mb + mt * 16 + l16) * 32 + rch];
        #pragma unroll
        for (int nt = 0; nt < 4; nt++) bf[nt] = *(const short8*)&bs[(nb + nt * 16 + l16) * 32 + rch];
        #pragma unroll
        for (int mt = 0; mt < 4; mt++)
            #pragma unroll
            for (int nt = 0; nt < 4; nt++)
                acc[mt][nt] = __builtin_amdgcn_mfma_f32_16x16x32_bf16(af[mt], bf[nt], acc[mt][nt], 0, 0, 0);
        __syncthreads();
        cur ^= 1;
    }
    #pragma unroll
    for (int mt = 0; mt < 4; mt++)
        #pragma unroll
        for (int nt = 0; nt < 4; nt++)
            #pragma unroll
            for (int r = 0; r < 4; r++)
                pre[(size_t)(bm0 + mb + mt * 16 + quad * 4 + r) * LL + (nb + nt * 16 + l16)] = acc[mt][nt][r];
}

// ---------------- GJ eliminate step k (separate launch, R2-proven), fused next-diag
// inversion via register-resident inv64_core ----------------
__global__ __launch_bounds__(256) void k_elim(float* __restrict__ Agj, float* __restrict__ invD, int k) {
    __shared__ __align__(16) float invDs[64 * 68];
    __shared__ __align__(16) float Ps[64 * 68];
    __shared__ __align__(16) float Ss[64 * 68];
    __shared__ __align__(16) float Ms[64 * 68];
    int tid = threadIdx.x;
    int by = blockIdx.y, bx = blockIdx.x;
    int rb = by + (by >= k ? 1 : 0);
    int cb = k + 1 + bx;
    int lr = tid >> 2, lc = tid & 3;
    #pragma unroll
    for (int q = 0; q < 4; q++) {
        *(f32x4*)&invDs[lr * 68 + lc * 16 + q * 4] = *(const f32x4*)(invD + (size_t)k * 4096 + lr * 64 + lc * 16 + q * 4);
        *(f32x4*)&Ps[lr * 68 + lc * 16 + q * 4]    = *(const f32x4*)(Agj + (size_t)(k * 64 + lr) * 1280 + cb * 64 + lc * 16 + q * 4);
        *(f32x4*)&Ms[lr * 68 + lc * 16 + q * 4]    = *(const f32x4*)(Agj + (size_t)(rb * 64 + lr) * 1280 + k * 64 + lc * 16 + q * 4);
    }
    __syncthreads();
    int ty = tid >> 4, tx = tid & 15;
    f32x4 s[4];
    #pragma unroll
    for (int ri = 0; ri < 4; ri++) s[ri] = (f32x4){0.f, 0.f, 0.f, 0.f};
    for (int kk = 0; kk < 64; kk++) {
        f32x4 pv = *(f32x4*)&Ps[kk * 68 + tx * 4];
        #pragma unroll
        for (int ri = 0; ri < 4; ri++) s[ri] += pv * invDs[(ty * 4 + ri) * 68 + kk];
    }
    #pragma unroll
    for (int ri = 0; ri < 4; ri++) *(f32x4*)&Ss[(ty * 4 + ri) * 68 + tx * 4] = s[ri];
    __syncthreads();
    f32x4 accv[4];
    #pragma unroll
    for (int ri = 0; ri < 4; ri++)
        accv[ri] = *(const f32x4*)(Agj + (size_t)(rb * 64 + ty * 4 + ri) * 1280 + cb * 64 + tx * 4);
    for (int kk = 0; kk < 64; kk++) {
        f32x4 sv = *(f32x4*)&Ss[kk * 68 + tx * 4];
        #pragma unroll
        for (int ri = 0; ri < 4; ri++) accv[ri] -= sv * Ms[(ty * 4 + ri) * 68 + kk];
    }
    #pragma unroll
    for (int ri = 0; ri < 4; ri++)
        *(f32x4*)(Agj + (size_t)(rb * 64 + ty * 4 + ri) * 1280 + cb * 64 + tx * 4) = accv[ri];
    if (k < 7 && bx == 0 && by == k) {
        // stage the freshly-updated (k+1,k+1) block into LDS, then wave 0 inverts it
        __syncthreads();
        #pragma unroll
        for (int ri = 0; ri < 4; ri++) *(f32x4*)&Ps[(ty * 4 + ri) * 68 + tx * 4] = accv[ri];
        __syncthreads();
        if (tid < 64) {
            float a[64];
            #pragma unroll
            for (int j4 = 0; j4 < 16; ++j4) {
                f32x4 v = *(const f32x4*)&Ps[tid * 68 + j4 * 4];
                a[j4*4+0]=v[0]; a[j4*4+1]=v[1]; a[j4*4+2]=v[2]; a[j4*4+3]=v[3];
            }
            inv64_core(a, tid);
            #pragma unroll
            for (int j4 = 0; j4 < 16; ++j4)
                *(f32x4*)(invD + (size_t)(k + 1) * 4096 + (size_t)tid * 64 + j4 * 4) =
                    (f32x4){a[j4*4], a[j4*4+1], a[j4*4+2], a[j4*4+3]};
        }
    }
}

// ---------------- finalize: Wc rows 0..511 = invD_k @ Agj[pivot rows, 512:1280] (bf16);
// rows 512..575 from C2|D21|D22; rows 576..639 zero padding ----------------
__global__ __launch_bounds__(256) void k_finalize(const float* __restrict__ Agj, const float* __restrict__ invD,
                                                  const float* __restrict__ C2, const float* __restrict__ D21,
                                                  const float* __restrict__ D22, u16* __restrict__ Wc) {
    __shared__ __align__(16) float invDs[64 * 68];
    __shared__ __align__(16) float Ps[64 * 68];
    int tid = threadIdx.x, bx = blockIdx.x, by = blockIdx.y;
    int ty = tid >> 4, tx = tid & 15;
    if (by >= 8) {
        #pragma unroll
        for (int ri = 0; ri < 4; ri++) {
            int q = ty * 4 + ri;
            int row = 512 + (by - 8) * 64 + q;
            int cbase = bx * 64 + tx * 4;
            short4v o;
            if (by == 8) {
                f32x4 v;
                if (cbase < 512)      v = *(const f32x4*)(C2 + (size_t)q * 512 + cbase);
                else if (cbase < 640) v = *(const f32x4*)(D21 + (size_t)q * NST + (cbase - 512));
                else                  v = *(const f32x4*)(D22 + (size_t)q * NST + (cbase - 640));
                o[0]=(short)f2bf(v[0]); o[1]=(short)f2bf(v[1]); o[2]=(short)f2bf(v[2]); o[3]=(short)f2bf(v[3]);
            } else {
                o[0]=0; o[1]=0; o[2]=0; o[3]=0;
            }
            *(short4v*)(Wc + (size_t)row * KC + cbase) = o;
        }
        return;
    }
    int lr = tid >> 2, lc = tid & 3;
    #pragma unroll
    for (int q = 0; q < 4; q++) {
        *(f32x4*)&invDs[lr * 68 + lc * 16 + q * 4] = *(const f32x4*)(invD + (size_t)by * 4096 + lr * 64 + lc * 16 + q * 4);
        *(f32x4*)&Ps[lr * 68 + lc * 16 + q * 4]    = *(const f32x4*)(Agj + (size_t)(by * 64 + lr) * 1280 + 512 + bx * 64 + lc * 16 + q * 4);
    }
    __syncthreads();
    f32x4 s[4];
    #pragma unroll
    for (int ri = 0; ri < 4; ri++) s[ri] = (f32x4){0.f, 0.f, 0.f, 0.f};
    for (int kk = 0; kk < 64; kk++) {
        f32x4 pv = *(f32x4*)&Ps[kk * 68 + tx * 4];
        #pragma unroll
        for (int ri = 0; ri < 4; ri++) s[ri] += pv * invDs[(ty * 4 + ri) * 68 + kk];
    }
    #pragma unroll
    for (int ri = 0; ri < 4; ri++) {
        short4v o; o[0]=(short)f2bf(s[ri][0]); o[1]=(short)f2bf(s[ri][1]); o[2]=(short)f2bf(s[ri][2]); o[3]=(short)f2bf(s[ri][3]);
        *(short4v*)(Wc + (size_t)(by * 64 + ty * 4 + ri) * KC + bx * 64 + tx * 4) = o;
    }
}

// ---------------- blocked sequential tanh scan (right-looking), 16 lanes per batch row ----------------
__global__ __launch_bounds__(1024) void k_scan(const float* __restrict__ pre, const float* __restrict__ D11,
                                               const float* __restrict__ rlam, u16* __restrict__ Ac) {
    __shared__ __align__(16) float D11s[128 * 132];   // +4 pad: row-per-lane reads are 2-way (free)
    int tid = threadIdx.x;
    {
        int r = tid >> 3, c = (tid & 7) * 16;
        const f32x4* src = (const f32x4*)(D11 + (size_t)r * 128 + c);
        f32x4 v0 = src[0], v1 = src[1], v2 = src[2], v3 = src[3];
        f32x4* dst = (f32x4*)&D11s[r * 132 + c];
        dst[0] = v0; dst[1] = v1; dst[2] = v2; dst[3] = v3;
    }
    int lg = tid & 15;
    int row = blockIdx.x * 64 + (tid >> 4);
    int gbase = (tid & 63) & ~15;
    const float L2E2 = 2.885390082f; // 2*log2(e)

    float corrv[8], a8[8];
    #pragma unroll
    for (int b = 0; b < 8; b++) {
        corrv[b] = pre[(size_t)row * 128 + b * 16 + lg];
        a8[b] = L2E2 * rlam[b * 16 + lg];
    }
    __syncthreads();

    #pragma unroll
    for (int b = 0; b < 8; b++) {
        f32x4 dblk[4];
        #pragma unroll
        for (int q = 0; q < 4; q++)
            dblk[q] = *(const f32x4*)&D11s[(b * 16 + lg) * 132 + b * 16 + q * 4];
        float v = corrv[b];
        float a = a8[b];
        float e16[16];
        float myeps = 0.f;
        #pragma unroll
        for (int t = 0; t < 16; t++) {
            float ex = __builtin_amdgcn_exp2f(a * v);
            float cand = 1.0f - 2.0f * __builtin_amdgcn_rcpf(ex + 1.0f);
            float e = __shfl(cand, gbase + t, 64);
            e16[t] = e;
            if (lg == t) myeps = e;
            v = fmaf(e, dblk[t >> 2][t & 3], v);
        }
        Ac[(size_t)row * KC + 512 + b * 16 + lg] = f2bf(myeps);
        #pragma unroll
        for (int bb = b + 1; bb < 8; bb++) {
            f32x4 dd[4];
            #pragma unroll
            for (int q = 0; q < 4; q++)
                dd[q] = *(const f32x4*)&D11s[(bb * 16 + lg) * 132 + b * 16 + q * 4];
            float acc = corrv[bb];
            #pragma unroll
            for (int t = 0; t < 16; t++)
                acc = fmaf(e16[t], dd[t >> 2][t & 3], acc);
            corrv[bb] = acc;
        }
    }
}

// ---------------- host ----------------
extern "C" void kernel_launch(void* const* d_in, const int* in_sizes, int n_in,
                              void* d_out, int out_size, void* d_ws, size_t ws_size,
                              hipStream_t stream) {
    const float* w_in  = (const float*)d_in[1];
    const float* xi_in = (const float*)d_in[2];
    const float* X   = (const float*)d_in[3];
    const float* Y   = (const float*)d_in[4];
    const float* B2  = (const float*)d_in[5];
    const float* C2  = (const float*)d_in[6];
    const float* D21 = (const float*)d_in[7];
    const float* D22 = (const float*)d_in[8];
    const float* D12 = (const float*)d_in[9];
    float* out_u  = (float*)d_out;                       // (BATCH,1,64)
    float* out_xi = (float*)d_out + (size_t)BATCH * NU;  // (BATCH,1,512)

    char* base = (char*)d_ws;
    size_t off = 0;
    auto carve = [&](size_t bytes) -> void* {
        void* p = base + off;
        off += (bytes + 255) & ~(size_t)255;
        return p;
    };
    u16*   XT   = (u16*)  carve((size_t)TW * TW * 2);
    u16*   Ac   = (u16*)  carve((size_t)BATCH * KC * 2);
    float* Hm   = (float*)carve((size_t)TW * TW * 4);
    float* Agj  = (float*)carve((size_t)512 * 1280 * 4);
    float* invD = (float*)carve((size_t)8 * 64 * 64 * 4);
    u16*   Wc   = (u16*)  carve((size_t)NCP * KC * 2);
    u16*   W1   = (u16*)  carve((size_t)LL * KC * 2);
    float* pre  = (float*)carve((size_t)BATCH * LL * 4);
    float* D11  = (float*)carve((size_t)LL * LL * 4);
    float* rlam = (float*)carve((size_t)LL * 4);
    (void)ws_size; (void)in_sizes; (void)n_in; (void)out_size;

    // fused setup: transpose (1296 blocks) + build Ac (10240 blocks)
    k_setup<<<1296 + BATCH * 80 / 256, 256, 0, stream>>>(X, XT, xi_in, w_in, Ac);
    // H = X^T X  (bf16 MFMA; +eps*I applied in k_derive). M=N=K=1152
    k_gemm2<<<81, 256, 0, stream>>>(XT, TW, XT, TW, Hm, TW, 1 << 30, nullptr, 0, TW, 9, TW, 0);
    k_derive<<<(512 * 1280 + 128 * 128 + 128 + 128 * KC + 255) / 256, 256, 0, stream>>>(
        Hm, Y, B2, D12, Agj, D11, rlam, W1);
    // diag-0 inversion (readlane, wave 0 of block 0) + piggybacked pre-GEMM (blocks 1..256)
    k_diaginv0<<<257, 256, 0, stream>>>(Agj, invD, Ac, W1, pre);
    // blocked Gauss-Jordan, separate launches (R2-proven), fused next-diag inversion
    for (int k = 0; k < 8; k++)
        k_elim<<<dim3(19 - k, 7), 256, 0, stream>>>(Agj, invD, k);
    k_finalize<<<dim3(12, 10), 256, 0, stream>>>(Agj, invD, C2, D21, D22, Wc);
    k_scan<<<BATCH / 64, 1024, 0, stream>>>(pre, D11, rlam, Ac);
    k_gemm2<<<1280, 256, 0, stream>>>(Ac, KC, Wc, KC, out_xi, NXI, 512, out_u, NU, KC, 5, NC, 1);
}

// Round 8
// 479.425 us; speedup vs baseline: 2.8965x; 2.8965x over previous
//
#include <hip/hip_runtime.h>
#include <cstddef>

// ---------------- constants ----------------
#define NXI   512
#define LL    128
#define NST   128
#define NU    64
#define BATCH 32768
#define TW    1152          // 2n + l
#define EPSC  0.001f
#define KC    768           // concat K: xi(512) | eps(128) | w(128)
#define NC    576           // concat N: xi'(512) | u(64)
#define NCP   640           // NC padded to 128

typedef unsigned short u16;
typedef __attribute__((ext_vector_type(8))) short   short8;
typedef __attribute__((ext_vector_type(4))) short   short4v;
typedef __attribute__((ext_vector_type(4))) float   f32x4;

__device__ __forceinline__ u16 f2bf(float f) {
    unsigned u = __float_as_uint(f);
    u += 0x7FFFu + ((u >> 16) & 1u);   // RNE
    return (u16)(u >> 16);
}

// ---------------- fused setup: transpose+convert X -> XT (blocks 0..1295),
// build Ac = [bf16(xi) | (eps gap) | bf16(w)] (blocks 1296..11535). ----------------
__global__ __launch_bounds__(256) void k_setup(const float* __restrict__ X, u16* __restrict__ XT,
                                               const float* __restrict__ xi, const float* __restrict__ w,
                                               u16* __restrict__ Ac) {
    __shared__ float t[32][33];
    int blk = blockIdx.x;
    if (blk < 1296) {
        int tx = threadIdx.x & 31, ty = threadIdx.x >> 5;
        int bx = blk % 36, by = blk / 36;
        #pragma unroll
        for (int q = 0; q < 4; q++) {
            int r = ty + q * 8;
            t[r][tx] = X[(size_t)(by * 32 + r) * TW + bx * 32 + tx];
        }
        __syncthreads();
        #pragma unroll
        for (int q = 0; q < 4; q++) {
            int r = ty + q * 8;
            XT[(size_t)(bx * 32 + r) * TW + by * 32 + tx] = f2bf(t[tx][r]);
        }
        return;
    }
    size_t tt = (size_t)(blk - 1296) * 256 + threadIdx.x;   // chunk id, 8 elems each
    int b = (int)(tt / 80), ch = (int)(tt % 80);
    const float* src;
    int col;
    if (ch < 64) { src = xi + (size_t)b * NXI + ch * 8;        col = ch * 8; }
    else         { src = w  + (size_t)b * NST + (ch - 64) * 8; col = 640 + (ch - 64) * 8; }
    f32x4 a = ((const f32x4*)src)[0], c = ((const f32x4*)src)[1];
    short8 o;
    o[0]=(short)f2bf(a[0]); o[1]=(short)f2bf(a[1]); o[2]=(short)f2bf(a[2]); o[3]=(short)f2bf(a[3]);
    o[4]=(short)f2bf(c[0]); o[5]=(short)f2bf(c[1]); o[6]=(short)f2bf(c[2]); o[7]=(short)f2bf(c[3]);
    *(short8*)(Ac + (size_t)b * KC + col) = o;
}

// ---------------- 2-phase double-buffered bf16 MFMA GEMM: C = A @ W^T ----------------
__global__ __launch_bounds__(256) void k_gemm2(const u16* __restrict__ A, int lda,
                                               const u16* __restrict__ W, int ldw,
                                               float* __restrict__ C0, int ldc0, int nsplit,
                                               float* __restrict__ C1, int ldc1,
                                               int K, int nbx, int ntrue, int swz) {
    __shared__ __align__(16) u16 As[2][128 * 32];
    __shared__ __align__(16) u16 Bs[2][128 * 32];
    int id = blockIdx.x;
    int bx, by;
    if (swz) {
        int j = id >> 3;
        int per = (int)(gridDim.x >> 3) / nbx;     // M-bands per XCD (requires nby%8==0)
        by = (id & 7) * per + j / nbx;
        bx = j - (j / nbx) * nbx;
    } else {
        by = id / nbx;
        bx = id - by * nbx;
    }
    const int tid = threadIdx.x;
    const int wave = tid >> 6, lane = tid & 63, quad = lane >> 4, l16 = lane & 15;
    const int bm0 = by * 128, bn0 = bx * 128;
    const int srow = tid >> 2;
    const int sch = (((tid & 3) ^ ((srow >> 2) & 3))) * 8;   // pre-swizzled source chunk
    const u16* ga0 = A + (size_t)(bm0 + srow) * lda + sch;
    const u16* ga1 = ga0 + (size_t)64 * lda;
    const u16* gb0 = W + (size_t)(bn0 + srow) * ldw + sch;
    const u16* gb1 = gb0 + (size_t)64 * ldw;
    const int lo = wave * 512;     // wave-uniform LDS dest (lane-ordered, contiguous)
    const int mb = (wave >> 1) * 64, nb = (wave & 1) * 64;
    const int rch = (quad ^ (l16 >> 2)) * 8;                 // swizzled read chunk

    f32x4 acc[4][4];
    #pragma unroll
    for (int i = 0; i < 4; i++)
        #pragma unroll
        for (int j = 0; j < 4; j++) acc[i][j] = (f32x4){0.f, 0.f, 0.f, 0.f};

    const int nk = K >> 5;
    __builtin_amdgcn_global_load_lds((void*)(ga0), (void*)(As[0] + lo),        16, 0, 0);
    __builtin_amdgcn_global_load_lds((void*)(ga1), (void*)(As[0] + lo + 2048), 16, 0, 0);
    __builtin_amdgcn_global_load_lds((void*)(gb0), (void*)(Bs[0] + lo),        16, 0, 0);
    __builtin_amdgcn_global_load_lds((void*)(gb1), (void*)(Bs[0] + lo + 2048), 16, 0, 0);
    __syncthreads();
    int cur = 0;
    for (int t = 0; t < nk; ++t) {
        if (t + 1 < nk) {
            const int kt = (t + 1) << 5;
            const int nx = cur ^ 1;
            __builtin_amdgcn_global_load_lds((void*)(ga0 + kt), (void*)(As[nx] + lo),        16, 0, 0);
            __builtin_amdgcn_global_load_lds((void*)(ga1 + kt), (void*)(As[nx] + lo + 2048), 16, 0, 0);
            __builtin_amdgcn_global_load_lds((void*)(gb0 + kt), (void*)(Bs[nx] + lo),        16, 0, 0);
            __builtin_amdgcn_global_load_lds((void*)(gb1 + kt), (void*)(Bs[nx] + lo + 2048), 16, 0, 0);
        }
        const u16* as = As[cur];
        const u16* bs = Bs[cur];
        short8 af[4], bf[4];
        #pragma unroll
        for (int mt = 0; mt < 4; mt++) af[mt] = *(const short8*)&as[(mb + mt * 16 + l16) * 32 + rch];
        #pragma unroll
        for (int nt = 0; nt < 4; nt++) bf[nt] = *(const short8*)&bs[(nb + nt * 16 + l16) * 32 + rch];
        #pragma unroll
        for (int mt = 0; mt < 4; mt++)
            #pragma unroll
            for (int nt = 0; nt < 4; nt++)
                acc[mt][nt] = __builtin_amdgcn_mfma_f32_16x16x32_bf16(af[mt], bf[nt], acc[mt][nt], 0, 0, 0);
        __syncthreads();
        cur ^= 1;
    }
    #pragma unroll
    for (int mt = 0; mt < 4; mt++)
        #pragma unroll
        for (int nt = 0; nt < 4; nt++)
            #pragma unroll
            for (int r = 0; r < 4; r++) {
                int row = bm0 + mb + mt * 16 + quad * 4 + r;
                int col = bn0 + nb + nt * 16 + l16;
                if (col < ntrue) {
                    float v = acc[mt][nt][r];
                    if (col < nsplit) C0[(size_t)row * ldc0 + col] = v;
                    else              C1[(size_t)row * ldc1 + (col - nsplit)] = v;
                }
            }
}

// ---------------- derive params from H, build GJ-augmented [E | Fm B1 B2], D11, rlam, W1 ----------------
__global__ __launch_bounds__(256) void k_derive(const float* __restrict__ Hm, const float* __restrict__ Y,
                                                const float* __restrict__ B2, const float* __restrict__ D12,
                                                float* __restrict__ Agj, float* __restrict__ D11,
                                                float* __restrict__ rlam, u16* __restrict__ W1) {
    int idx = blockIdx.x * 256 + threadIdx.x;
    const int n0 = 512 * 1280, n1 = 128 * 128, n2 = 128, n3 = 128 * KC;
    if (idx < n0) {
        int i = idx / 1280, j = idx % 1280;
        float val;
        if (j < 512) {
            val = 0.5f * (Hm[(size_t)i * TW + j] + Hm[(size_t)(640 + i) * TW + 640 + j]
                          + Y[(size_t)i * 512 + j] - Y[(size_t)j * 512 + i]);
            if (i == j) val += EPSC;
        } else if (j < 1024) {
            val = Hm[(size_t)(640 + i) * TW + (j - 512)];           // Fm = H31
        } else if (j < 1152) {
            val = Hm[(size_t)(640 + i) * TW + 512 + (j - 1024)];    // B1 = H32
        } else {
            val = B2[(size_t)i * NST + (j - 1152)];
        }
        Agj[idx] = val;
        return;
    }
    idx -= n0;
    if (idx < n1) {
        int i = idx >> 7, j = idx & 127;
        D11[idx] = (j < i) ? -Hm[(size_t)(512 + i) * TW + 512 + j] : 0.f;  // -tril(H22,-1)
        return;
    }
    idx -= n1;
    if (idx < n2) {
        rlam[idx] = 2.0f / (Hm[(size_t)(512 + idx) * TW + 512 + idx] + EPSC);  // 1/(0.5*diag(H22))
        return;
    }
    idx -= n2;
    if (idx < n3) {
        int i = idx / KC, c = idx % KC;
        float v;
        if (c < 512)      v = -Hm[(size_t)(512 + i) * TW + c];      // C1 = -H21
        else if (c < 640) v = 0.f;                                  // eps slot unused for pre
        else              v = D12[(size_t)i * NST + (c - 640)];
        W1[(size_t)i * KC + c] = f2bf(v);
    }
}

// ---------------- 64x64 IN-PLACE Gauss-Jordan inverse, 4 waves, 1 barrier/iter ----------------
// Math = R6-verified in-place transform (no augmented B => half the FMAs of R2's
// invert64): pivot row -> ip*row (col k -> ip); other rows -> row - m*ip*srow
// (col k -> -m*ip). Structure = R2/R5-proven 4-wave layout (thread (r,c) owns 16
// elements of row r) with parity-double-buffered Sa/mcol/rp broadcast -> single
// __syncthreads per pivot. R7's register/readlane variant is DEAD: compiler kept the
// outer loop rolled -> runtime-indexed array -> scratch -> 257 us (rule #20).
__device__ __forceinline__ void invert64ip(float* Cl, float* Sa, float* mcol, float* rp,
                                           float* __restrict__ invOut, int tid) {
    int r = tid >> 2, c = tid & 3;
    float a[16];
    #pragma unroll
    for (int q = 0; q < 4; q++) {
        f32x4 v = *(f32x4*)&Cl[r * 68 + c * 16 + q * 4];
        a[q*4+0]=v[0]; a[q*4+1]=v[1]; a[q*4+2]=v[2]; a[q*4+3]=v[3];
    }
    #pragma unroll
    for (int k = 0; k < 64; k++) {
        const int p = (k & 1) << 6;   // parity double-buffer offset
        const int kc = k >> 4, kl = k & 15;
        if (r == k) {
            #pragma unroll
            for (int q = 0; q < 4; q++)
                *(f32x4*)&Sa[p + c * 16 + q * 4] = (f32x4){a[q*4], a[q*4+1], a[q*4+2], a[q*4+3]};
        }
        if (c == kc) {
            mcol[p + r] = a[kl];
            if (r == k) rp[k & 1] = 1.0f / a[kl];
        }
        __syncthreads();
        const bool piv = (r == k);
        float ip = rp[k & 1];
        float m  = mcol[p + r];
        float tm = piv ? ip : -m * ip;
        #pragma unroll
        for (int j = 0; j < 16; j++) {
            float sj = Sa[p + c * 16 + j];
            a[j] = fmaf(tm, sj, piv ? 0.f : a[j]);
        }
        if (c == kc) a[kl] = tm;   // column-k fix (overwrites the fma result)
    }
    #pragma unroll
    for (int q = 0; q < 4; q++)
        *(f32x4*)&invOut[r * 64 + c * 16 + q * 4] = (f32x4){a[q*4], a[q*4+1], a[q*4+2], a[q*4+3]};
}

// ---------------- diag block 0 inversion (block 0, 4 waves) +
// piggyback pre-GEMM (blocks 1..256): pre = Ac @ W1^T. Independent outputs, no sync. ----------------
__global__ __launch_bounds__(256) void k_diaginv0(const float* __restrict__ Agj, float* __restrict__ invD,
                                                  const u16* __restrict__ Ac, const u16* __restrict__ W1,
                                                  float* __restrict__ pre) {
    __shared__ __align__(16) u16 AsB[2][4096];
    __shared__ __align__(16) u16 BsB[2][4096];
    __shared__ __align__(16) float Cl[64 * 68];
    __shared__ float Sa[128], mcol[128], rp[2];
    const int tid = threadIdx.x;
    const int id = blockIdx.x;
    if (id == 0) {
        int r = tid >> 2, c4 = tid & 3;
        #pragma unroll
        for (int q = 0; q < 4; q++)
            *(f32x4*)&Cl[r * 68 + c4 * 16 + q * 4] = *(const f32x4*)(Agj + (size_t)r * 1280 + c4 * 16 + q * 4);
        __syncthreads();
        invert64ip(Cl, Sa, mcol, rp, invD, tid);
        return;
    }
    // ---- pre-GEMM tile (R5-verified body), by = id-1 over M=32768 ----
    const int by = id - 1;
    const int wave = tid >> 6, lane = tid & 63, quad = lane >> 4, l16 = lane & 15;
    const int bm0 = by * 128;
    const int srow = tid >> 2;
    const int sch = (((tid & 3) ^ ((srow >> 2) & 3))) * 8;
    const u16* ga0 = Ac + (size_t)(bm0 + srow) * KC + sch;
    const u16* ga1 = ga0 + (size_t)64 * KC;
    const u16* gb0 = W1 + (size_t)srow * KC + sch;
    const u16* gb1 = gb0 + (size_t)64 * KC;
    const int lo = wave * 512;
    const int mb = (wave >> 1) * 64, nb = (wave & 1) * 64;
    const int rch = (quad ^ (l16 >> 2)) * 8;
    f32x4 acc[4][4];
    #pragma unroll
    for (int i = 0; i < 4; i++)
        #pragma unroll
        for (int j = 0; j < 4; j++) acc[i][j] = (f32x4){0.f, 0.f, 0.f, 0.f};
    __builtin_amdgcn_global_load_lds((void*)(ga0), (void*)(AsB[0] + lo),        16, 0, 0);
    __builtin_amdgcn_global_load_lds((void*)(ga1), (void*)(AsB[0] + lo + 2048), 16, 0, 0);
    __builtin_amdgcn_global_load_lds((void*)(gb0), (void*)(BsB[0] + lo),        16, 0, 0);
    __builtin_amdgcn_global_load_lds((void*)(gb1), (void*)(BsB[0] + lo + 2048), 16, 0, 0);
    __syncthreads();
    int cur = 0;
    for (int t = 0; t < 24; ++t) {
        if (t + 1 < 24) {
            const int kt = (t + 1) << 5;
            const int nx = cur ^ 1;
            __builtin_amdgcn_global_load_lds((void*)(ga0 + kt), (void*)(AsB[nx] + lo),        16, 0, 0);
            __builtin_amdgcn_global_load_lds((void*)(ga1 + kt), (void*)(AsB[nx] + lo + 2048), 16, 0, 0);
            __builtin_amdgcn_global_load_lds((void*)(gb0 + kt), (void*)(BsB[nx] + lo),        16, 0, 0);
            __builtin_amdgcn_global_load_lds((void*)(gb1 + kt), (void*)(BsB[nx] + lo + 2048), 16, 0, 0);
        }
        const u16* as = AsB[cur];
        const u16* bs = BsB[cur];
        short8 af[4], bf[4];
        #pragma unroll
        for (int mt = 0; mt < 4; mt++) af[mt] = *(const short8*)&as[(mb + mt * 16 + l16) * 32 + rch];
        #pragma unroll
        for (int nt = 0; nt < 4; nt++) bf[nt] = *(const short8*)&bs[(nb + nt * 16 + l16) * 32 + rch];
        #pragma unroll
        for (int mt = 0; mt < 4; mt++)
            #pragma unroll
            for (int nt = 0; nt < 4; nt++)
                acc[mt][nt] = __builtin_amdgcn_mfma_f32_16x16x32_bf16(af[mt], bf[nt], acc[mt][nt], 0, 0, 0);
        __syncthreads();
        cur ^= 1;
    }
    #pragma unroll
    for (int mt = 0; mt < 4; mt++)
        #pragma unroll
        for (int nt = 0; nt < 4; nt++)
            #pragma unroll
            for (int r = 0; r < 4; r++)
                pre[(size_t)(bm0 + mb + mt * 16 + quad * 4 + r) * LL + (nb + nt * 16 + l16)] = acc[mt][nt][r];
}

// ---------------- GJ eliminate step k (separate launch, R2-proven), fused next-diag
// inversion via 4-wave in-place invert64ip ----------------
__global__ __launch_bounds__(256) void k_elim(float* __restrict__ Agj, float* __restrict__ invD, int k) {
    __shared__ __align__(16) float invDs[64 * 68];
    __shared__ __align__(16) float Ps[64 * 68];
    __shared__ __align__(16) float Ss[64 * 68];
    __shared__ __align__(16) float Ms[64 * 68];
    __shared__ float Sa[128], mcol[128], rp[2];
    int tid = threadIdx.x;
    int by = blockIdx.y, bx = blockIdx.x;
    int rb = by + (by >= k ? 1 : 0);
    int cb = k + 1 + bx;
    int lr = tid >> 2, lc = tid & 3;
    #pragma unroll
    for (int q = 0; q < 4; q++) {
        *(f32x4*)&invDs[lr * 68 + lc * 16 + q * 4] = *(const f32x4*)(invD + (size_t)k * 4096 + lr * 64 + lc * 16 + q * 4);
        *(f32x4*)&Ps[lr * 68 + lc * 16 + q * 4]    = *(const f32x4*)(Agj + (size_t)(k * 64 + lr) * 1280 + cb * 64 + lc * 16 + q * 4);
        *(f32x4*)&Ms[lr * 68 + lc * 16 + q * 4]    = *(const f32x4*)(Agj + (size_t)(rb * 64 + lr) * 1280 + k * 64 + lc * 16 + q * 4);
    }
    __syncthreads();
    int ty = tid >> 4, tx = tid & 15;
    f32x4 s[4];
    #pragma unroll
    for (int ri = 0; ri < 4; ri++) s[ri] = (f32x4){0.f, 0.f, 0.f, 0.f};
    for (int kk = 0; kk < 64; kk++) {
        f32x4 pv = *(f32x4*)&Ps[kk * 68 + tx * 4];
        #pragma unroll
        for (int ri = 0; ri < 4; ri++) s[ri] += pv * invDs[(ty * 4 + ri) * 68 + kk];
    }
    #pragma unroll
    for (int ri = 0; ri < 4; ri++) *(f32x4*)&Ss[(ty * 4 + ri) * 68 + tx * 4] = s[ri];
    __syncthreads();
    f32x4 accv[4];
    #pragma unroll
    for (int ri = 0; ri < 4; ri++)
        accv[ri] = *(const f32x4*)(Agj + (size_t)(rb * 64 + ty * 4 + ri) * 1280 + cb * 64 + tx * 4);
    for (int kk = 0; kk < 64; kk++) {
        f32x4 sv = *(f32x4*)&Ss[kk * 68 + tx * 4];
        #pragma unroll
        for (int ri = 0; ri < 4; ri++) accv[ri] -= sv * Ms[(ty * 4 + ri) * 68 + kk];
    }
    #pragma unroll
    for (int ri = 0; ri < 4; ri++)
        *(f32x4*)(Agj + (size_t)(rb * 64 + ty * 4 + ri) * 1280 + cb * 64 + tx * 4) = accv[ri];
    if (k < 7 && bx == 0 && by == k) {
        // stage the freshly-updated (k+1,k+1) block into LDS, then invert (4 waves)
        __syncthreads();
        #pragma unroll
        for (int ri = 0; ri < 4; ri++) *(f32x4*)&Ps[(ty * 4 + ri) * 68 + tx * 4] = accv[ri];
        __syncthreads();
        invert64ip(Ps, Sa, mcol, rp, invD + (size_t)(k + 1) * 4096, tid);
    }
}

// ---------------- finalize: Wc rows 0..511 = invD_k @ Agj[pivot rows, 512:1280] (bf16);
// rows 512..575 from C2|D21|D22; rows 576..639 zero padding ----------------
__global__ __launch_bounds__(256) void k_finalize(const float* __restrict__ Agj, const float* __restrict__ invD,
                                                  const float* __restrict__ C2, const float* __restrict__ D21,
                                                  const float* __restrict__ D22, u16* __restrict__ Wc) {
    __shared__ __align__(16) float invDs[64 * 68];
    __shared__ __align__(16) float Ps[64 * 68];
    int tid = threadIdx.x, bx = blockIdx.x, by = blockIdx.y;
    int ty = tid >> 4, tx = tid & 15;
    if (by >= 8) {
        #pragma unroll
        for (int ri = 0; ri < 4; ri++) {
            int q = ty * 4 + ri;
            int row = 512 + (by - 8) * 64 + q;
            int cbase = bx * 64 + tx * 4;
            short4v o;
            if (by == 8) {
                f32x4 v;
                if (cbase < 512)      v = *(const f32x4*)(C2 + (size_t)q * 512 + cbase);
                else if (cbase < 640) v = *(const f32x4*)(D21 + (size_t)q * NST + (cbase - 512));
                else                  v = *(const f32x4*)(D22 + (size_t)q * NST + (cbase - 640));
                o[0]=(short)f2bf(v[0]); o[1]=(short)f2bf(v[1]); o[2]=(short)f2bf(v[2]); o[3]=(short)f2bf(v[3]);
            } else {
                o[0]=0; o[1]=0; o[2]=0; o[3]=0;
            }
            *(short4v*)(Wc + (size_t)row * KC + cbase) = o;
        }
        return;
    }
    int lr = tid >> 2, lc = tid & 3;
    #pragma unroll
    for (int q = 0; q < 4; q++) {
        *(f32x4*)&invDs[lr * 68 + lc * 16 + q * 4] = *(const f32x4*)(invD + (size_t)by * 4096 + lr * 64 + lc * 16 + q * 4);
        *(f32x4*)&Ps[lr * 68 + lc * 16 + q * 4]    = *(const f32x4*)(Agj + (size_t)(by * 64 + lr) * 1280 + 512 + bx * 64 + lc * 16 + q * 4);
    }
    __syncthreads();
    f32x4 s[4];
    #pragma unroll
    for (int ri = 0; ri < 4; ri++) s[ri] = (f32x4){0.f, 0.f, 0.f, 0.f};
    for (int kk = 0; kk < 64; kk++) {
        f32x4 pv = *(f32x4*)&Ps[kk * 68 + tx * 4];
        #pragma unroll
        for (int ri = 0; ri < 4; ri++) s[ri] += pv * invDs[(ty * 4 + ri) * 68 + kk];
    }
    #pragma unroll
    for (int ri = 0; ri < 4; ri++) {
        short4v o; o[0]=(short)f2bf(s[ri][0]); o[1]=(short)f2bf(s[ri][1]); o[2]=(short)f2bf(s[ri][2]); o[3]=(short)f2bf(s[ri][3]);
        *(short4v*)(Wc + (size_t)(by * 64 + ty * 4 + ri) * KC + bx * 64 + tx * 4) = o;
    }
}

// ---------------- blocked sequential tanh scan (right-looking), 16 lanes per batch row ----------------
__global__ __launch_bounds__(1024) void k_scan(const float* __restrict__ pre, const float* __restrict__ D11,
                                               const float* __restrict__ rlam, u16* __restrict__ Ac) {
    __shared__ __align__(16) float D11s[128 * 132];   // +4 pad: row-per-lane reads are 2-way (free)
    int tid = threadIdx.x;
    {
        int r = tid >> 3, c = (tid & 7) * 16;
        const f32x4* src = (const f32x4*)(D11 + (size_t)r * 128 + c);
        f32x4 v0 = src[0], v1 = src[1], v2 = src[2], v3 = src[3];
        f32x4* dst = (f32x4*)&D11s[r * 132 + c];
        dst[0] = v0; dst[1] = v1; dst[2] = v2; dst[3] = v3;
    }
    int lg = tid & 15;
    int row = blockIdx.x * 64 + (tid >> 4);
    int gbase = (tid & 63) & ~15;
    const float L2E2 = 2.885390082f; // 2*log2(e)

    float corrv[8], a8[8];
    #pragma unroll
    for (int b = 0; b < 8; b++) {
        corrv[b] = pre[(size_t)row * 128 + b * 16 + lg];
        a8[b] = L2E2 * rlam[b * 16 + lg];
    }
    __syncthreads();

    #pragma unroll
    for (int b = 0; b < 8; b++) {
        f32x4 dblk[4];
        #pragma unroll
        for (int q = 0; q < 4; q++)
            dblk[q] = *(const f32x4*)&D11s[(b * 16 + lg) * 132 + b * 16 + q * 4];
        float v = corrv[b];
        float a = a8[b];
        float e16[16];
        float myeps = 0.f;
        #pragma unroll
        for (int t = 0; t < 16; t++) {
            float ex = __builtin_amdgcn_exp2f(a * v);
            float cand = 1.0f - 2.0f * __builtin_amdgcn_rcpf(ex + 1.0f);
            float e = __shfl(cand, gbase + t, 64);
            e16[t] = e;
            if (lg == t) myeps = e;
            v = fmaf(e, dblk[t >> 2][t & 3], v);
        }
        Ac[(size_t)row * KC + 512 + b * 16 + lg] = f2bf(myeps);
        #pragma unroll
        for (int bb = b + 1; bb < 8; bb++) {
            f32x4 dd[4];
            #pragma unroll
            for (int q = 0; q < 4; q++)
                dd[q] = *(const f32x4*)&D11s[(bb * 16 + lg) * 132 + b * 16 + q * 4];
            float acc = corrv[bb];
            #pragma unroll
            for (int t = 0; t < 16; t++)
                acc = fmaf(e16[t], dd[t >> 2][t & 3], acc);
            corrv[bb] = acc;
        }
    }
}

// ---------------- host ----------------
extern "C" void kernel_launch(void* const* d_in, const int* in_sizes, int n_in,
                              void* d_out, int out_size, void* d_ws, size_t ws_size,
                              hipStream_t stream) {
    const float* w_in  = (const float*)d_in[1];
    const float* xi_in = (const float*)d_in[2];
    const float* X   = (const float*)d_in[3];
    const float* Y   = (const float*)d_in[4];
    const float* B2  = (const float*)d_in[5];
    const float* C2  = (const float*)d_in[6];
    const float* D21 = (const float*)d_in[7];
    const float* D22 = (const float*)d_in[8];
    const float* D12 = (const float*)d_in[9];
    float* out_u  = (float*)d_out;                       // (BATCH,1,64)
    float* out_xi = (float*)d_out + (size_t)BATCH * NU;  // (BATCH,1,512)

    char* base = (char*)d_ws;
    size_t off = 0;
    auto carve = [&](size_t bytes) -> void* {
        void* p = base + off;
        off += (bytes + 255) & ~(size_t)255;
        return p;
    };
    u16*   XT   = (u16*)  carve((size_t)TW * TW * 2);
    u16*   Ac   = (u16*)  carve((size_t)BATCH * KC * 2);
    float* Hm   = (float*)carve((size_t)TW * TW * 4);
    float* Agj  = (float*)carve((size_t)512 * 1280 * 4);
    float* invD = (float*)carve((size_t)8 * 64 * 64 * 4);
    u16*   Wc   = (u16*)  carve((size_t)NCP * KC * 2);
    u16*   W1   = (u16*)  carve((size_t)LL * KC * 2);
    float* pre  = (float*)carve((size_t)BATCH * LL * 4);
    float* D11  = (float*)carve((size_t)LL * LL * 4);
    float* rlam = (float*)carve((size_t)LL * 4);
    (void)ws_size; (void)in_sizes; (void)n_in; (void)out_size;

    // fused setup: transpose (1296 blocks) + build Ac (10240 blocks)
    k_setup<<<1296 + BATCH * 80 / 256, 256, 0, stream>>>(X, XT, xi_in, w_in, Ac);
    // H = X^T X  (bf16 MFMA; +eps*I applied in k_derive). M=N=K=1152
    k_gemm2<<<81, 256, 0, stream>>>(XT, TW, XT, TW, Hm, TW, 1 << 30, nullptr, 0, TW, 9, TW, 0);
    k_derive<<<(512 * 1280 + 128 * 128 + 128 + 128 * KC + 255) / 256, 256, 0, stream>>>(
        Hm, Y, B2, D12, Agj, D11, rlam, W1);
    // diag-0 inversion (4-wave in-place) + piggybacked pre-GEMM (blocks 1..256)
    k_diaginv0<<<257, 256, 0, stream>>>(Agj, invD, Ac, W1, pre);
    // blocked Gauss-Jordan, separate launches (R2-proven), fused next-diag inversion
    for (int k = 0; k < 8; k++)
        k_elim<<<dim3(19 - k, 7), 256, 0, stream>>>(Agj, invD, k);
    k_finalize<<<dim3(12, 10), 256, 0, stream>>>(Agj, invD, C2, D21, D22, Wc);
    k_scan<<<BATCH / 64, 1024, 0, stream>>>(pre, D11, rlam, Ac);
    k_gemm2<<<1280, 256, 0, stream>>>(Ac, KC, Wc, KC, out_xi, NXI, 512, out_u, NU, KC, 5, NC, 1);
}